// Round 3
// baseline (563.960 us; speedup 1.0000x reference)
//
#include <hip/hip_runtime.h>

#define D_FEAT 64

// ---------------- utility ----------------

__global__ void zero_int_kernel(int* __restrict__ p, int n) {
    int i = blockIdx.x * blockDim.x + threadIdx.x;
    if (i < n) p[i] = 0;
}

// count[d] += 1 per edge (int atomics, cheap)
__global__ void count_kernel(const int* __restrict__ dst, int* __restrict__ count, int e) {
    int i = blockIdx.x * blockDim.x + threadIdx.x;
    if (i < e) atomicAdd(&count[dst[i]], 1);
}

// dinv[i] = rsqrt(1 + indeg)
__global__ void dinv_kernel(const int* __restrict__ count, float* __restrict__ dinv, int n) {
    int i = blockIdx.x * blockDim.x + threadIdx.x;
    if (i < n) dinv[i] = rsqrtf(1.0f + (float)count[i]);
}

// ---------------- exclusive scan (3 kernels) ----------------

// per-block (256) exclusive scan of count -> rp, block total -> bsum
__global__ __launch_bounds__(256) void scan_block_kernel(const int* __restrict__ count,
                                                         int* __restrict__ rp,
                                                         int* __restrict__ bsum, int n) {
    __shared__ int s[256];
    int tid = threadIdx.x;
    int i = blockIdx.x * 256 + tid;
    int v = (i < n) ? count[i] : 0;
    s[tid] = v;
    __syncthreads();
    // Hillis-Steele inclusive scan
    for (int off = 1; off < 256; off <<= 1) {
        int t = (tid >= off) ? s[tid - off] : 0;
        __syncthreads();
        s[tid] += t;
        __syncthreads();
    }
    if (i < n) rp[i] = s[tid] - v;  // exclusive
    if (tid == 255) bsum[blockIdx.x] = s[255];
}

// single-thread exclusive scan of block sums (nb ~ 391, runs once, trivial)
__global__ void scan_sums_kernel(int* __restrict__ bsum, int nb) {
    if (blockIdx.x == 0 && threadIdx.x == 0) {
        int run = 0;
        for (int i = 0; i < nb; ++i) {
            int t = bsum[i];
            bsum[i] = run;
            run += t;
        }
    }
}

__global__ __launch_bounds__(256) void scan_add_kernel(int* __restrict__ rp,
                                                       const int* __restrict__ bsum,
                                                       int n, int e) {
    int i = blockIdx.x * 256 + threadIdx.x;
    if (i < n) rp[i] += bsum[i >> 8];
    if (i == 0) rp[n] = e;
}

// ---------------- CSR fill ----------------

// col[pos] = src, wval[pos] = dinv[src]; pos allocated via per-node cursor
__global__ void fill_kernel(const int* __restrict__ src, const int* __restrict__ dst,
                            const int* __restrict__ rp, int* __restrict__ cursor,
                            const float* __restrict__ dinv,
                            int* __restrict__ col, float* __restrict__ wval, int e) {
    int i = blockIdx.x * blockDim.x + threadIdx.x;
    if (i >= e) return;
    int d = dst[i];
    int s = src[i];
    int pos = rp[d] + atomicAdd(&cursor[d], 1);
    col[pos] = s;
    wval[pos] = dinv[s];
}

// ---------------- gather SpMM hop ----------------
// out[d][:] = dinv[d] * ( dinv[d]*h[d][:] + sum_e wval[e]*h[col[e]][:] )
// 16 lanes per node, float4 per lane (64 floats per node row).

__global__ __launch_bounds__(256) void spmm_gather_kernel(const int* __restrict__ rp,
                                                          const int* __restrict__ col,
                                                          const float* __restrict__ wval,
                                                          const float* __restrict__ dinv,
                                                          const float* __restrict__ hin,
                                                          float* __restrict__ hout, int n) {
    int t = blockIdx.x * 256 + threadIdx.x;
    int node = t >> 4;
    int j = t & 15;
    if (node >= n) return;
    int e0 = rp[node];
    int e1 = rp[node + 1];
    float di = dinv[node];
    const float4* hin4 = (const float4*)hin;
    float4 acc = hin4[(size_t)node * 16 + j];
    acc.x *= di; acc.y *= di; acc.z *= di; acc.w *= di;
    for (int e = e0; e < e1; ++e) {
        int s = col[e];
        float w = wval[e];
        float4 v = hin4[(size_t)s * 16 + j];
        acc.x = fmaf(w, v.x, acc.x);
        acc.y = fmaf(w, v.y, acc.y);
        acc.z = fmaf(w, v.z, acc.z);
        acc.w = fmaf(w, v.w, acc.w);
    }
    acc.x *= di; acc.y *= di; acc.z *= di; acc.w *= di;
    ((float4*)hout)[(size_t)node * 16 + j] = acc;
}

// ---------------- output GEMM: [x | h1 | h2] @ W + b ----------------

#define GEMM_NODES 16

__global__ __launch_bounds__(256) void gemm_kernel(const float* __restrict__ x,
                                                   const float* __restrict__ h1,
                                                   const float* __restrict__ h2,
                                                   const float* __restrict__ W,
                                                   const float* __restrict__ b,
                                                   float* __restrict__ out, int n) {
    __shared__ float sW[192 * 64];            // 48 KB
    __shared__ float sF[GEMM_NODES][192];     // 12 KB
    int tid = threadIdx.x;
    int n0 = blockIdx.x * GEMM_NODES;

    for (int i = tid; i < 192 * 64; i += 256) sW[i] = W[i];

    for (int i = tid; i < GEMM_NODES * 192; i += 256) {
        int ln = i / 192;
        int k = i - ln * 192;
        int node = n0 + ln;
        float v = 0.0f;
        if (node < n) {
            const float* srcp = (k < 64) ? x : ((k < 128) ? h1 : h2);
            int kk = k & 63;
            v = srcp[(size_t)node * D_FEAT + kk];
        }
        sF[ln][k] = v;
    }
    __syncthreads();

    int c = tid & 63;
    int q = tid >> 6;  // 0..3 -> 4 nodes each
    float bias = b[c];
    for (int i = 0; i < 4; ++i) {
        int ln = q * 4 + i;
        int node = n0 + ln;
        if (node >= n) continue;
        float acc = bias;
#pragma unroll 16
        for (int k = 0; k < 192; ++k) acc = fmaf(sF[ln][k], sW[k * 64 + c], acc);
        out[(size_t)node * D_FEAT + c] = acc;
    }
}

// ---------------- launch ----------------

static inline size_t align256(size_t x) { return (x + 255) & ~(size_t)255; }

extern "C" void kernel_launch(void* const* d_in, const int* in_sizes, int n_in,
                              void* d_out, int out_size, void* d_ws, size_t ws_size,
                              hipStream_t stream) {
    const float* x  = (const float*)d_in[0];
    const int*   ei = (const int*)d_in[1];
    const float* W  = (const float*)d_in[2];
    const float* b  = (const float*)d_in[3];
    float* out = (float*)d_out;

    int N = in_sizes[0] / D_FEAT;
    int E = in_sizes[1] / 2;
    const int* src = ei;
    const int* dst = ei + E;

    // workspace carve (byte offsets, 256B aligned)
    char* base = (char*)d_ws;
    size_t off = 0;
    int* count  = (int*)(base + off);  off = align256(off + (size_t)N * 4);
    int* cursor = (int*)(base + off);  off = align256(off + (size_t)N * 4);
    int* rp     = (int*)(base + off);  off = align256(off + ((size_t)N + 1) * 4);
    int* bsum   = (int*)(base + off);  off = align256(off + 4096);
    float* dinv = (float*)(base + off); off = align256(off + (size_t)N * 4);
    int* col    = (int*)(base + off);  off = align256(off + (size_t)E * 4);
    float* wval = (float*)(base + off); off = align256(off + (size_t)E * 4);
    float* h1   = (float*)(base + off); off = align256(off + (size_t)N * D_FEAT * 4);
    float* h2   = (float*)(base + off); off = align256(off + (size_t)N * D_FEAT * 4);

    const int BS = 256;
    int gN   = (N + BS - 1) / BS;
    int gE   = (E + BS - 1) / BS;
    int nb   = gN;  // scan blocks of 256
    int gN16 = (int)(((long long)N * 16 + BS - 1) / BS);
    int gGemm = (N + GEMM_NODES - 1) / GEMM_NODES;

    // 1. zero count + cursor
    zero_int_kernel<<<(2 * N + BS - 1) / BS, BS, 0, stream>>>(count, 2 * N);  // count,cursor contiguous? not guaranteed -> do separately
    zero_int_kernel<<<gN, BS, 0, stream>>>(cursor, N);
    // 2. indegree count (int atomics)
    count_kernel<<<gE, BS, 0, stream>>>(dst, count, E);
    // 3. dinv = rsqrt(1 + indeg)
    dinv_kernel<<<gN, BS, 0, stream>>>(count, dinv, N);
    // 4. exclusive scan count -> rp
    scan_block_kernel<<<nb, BS, 0, stream>>>(count, rp, bsum, N);
    scan_sums_kernel<<<1, 64, 0, stream>>>(bsum, nb);
    scan_add_kernel<<<gN, BS, 0, stream>>>(rp, bsum, N, E);
    // 5. CSR fill
    fill_kernel<<<gE, BS, 0, stream>>>(src, dst, rp, cursor, dinv, col, wval, E);
    // 6. hop 1: h1 = gather(x)
    spmm_gather_kernel<<<gN16, BS, 0, stream>>>(rp, col, wval, dinv, x, h1, N);
    // 7. hop 2: h2 = gather(h1)
    spmm_gather_kernel<<<gN16, BS, 0, stream>>>(rp, col, wval, dinv, h1, h2, N);
    // 8. out = [x|h1|h2] @ W + b
    gemm_kernel<<<gGemm, BS, 0, stream>>>(x, h1, h2, W, b, out, N);
}

// Round 4
// 427.736 us; speedup vs baseline: 1.3185x; 1.3185x over previous
//
#include <hip/hip_runtime.h>

#define D_FEAT 64

typedef __attribute__((ext_vector_type(8))) short bf16x8;
typedef __attribute__((ext_vector_type(4))) float f32x4;

// ---------------- utility ----------------

__global__ void zero_int_kernel(int* __restrict__ p, int n) {
    int i = blockIdx.x * blockDim.x + threadIdx.x;
    if (i < n) p[i] = 0;
}

// count[d] += 1 per edge (int atomics, cheap)
__global__ void count_kernel(const int* __restrict__ dst, int* __restrict__ count, int e) {
    int i = blockIdx.x * blockDim.x + threadIdx.x;
    if (i < e) atomicAdd(&count[dst[i]], 1);
}

// dinv[i] = rsqrt(1 + indeg)
__global__ void dinv_kernel(const int* __restrict__ count, float* __restrict__ dinv, int n) {
    int i = blockIdx.x * blockDim.x + threadIdx.x;
    if (i < n) dinv[i] = rsqrtf(1.0f + (float)count[i]);
}

// ---------------- exclusive scan (3 kernels) ----------------

__global__ __launch_bounds__(256) void scan_block_kernel(const int* __restrict__ count,
                                                         int* __restrict__ rp,
                                                         int* __restrict__ bsum, int n) {
    __shared__ int s[256];
    int tid = threadIdx.x;
    int i = blockIdx.x * 256 + tid;
    int v = (i < n) ? count[i] : 0;
    s[tid] = v;
    __syncthreads();
    for (int off = 1; off < 256; off <<= 1) {
        int t = (tid >= off) ? s[tid - off] : 0;
        __syncthreads();
        s[tid] += t;
        __syncthreads();
    }
    if (i < n) rp[i] = s[tid] - v;  // exclusive
    if (tid == 255) bsum[blockIdx.x] = s[255];
}

__global__ void scan_sums_kernel(int* __restrict__ bsum, int nb) {
    if (blockIdx.x == 0 && threadIdx.x == 0) {
        int run = 0;
        for (int i = 0; i < nb; ++i) {
            int t = bsum[i];
            bsum[i] = run;
            run += t;
        }
    }
}

__global__ __launch_bounds__(256) void scan_add_kernel(int* __restrict__ rp,
                                                       const int* __restrict__ bsum,
                                                       int n, int e) {
    int i = blockIdx.x * 256 + threadIdx.x;
    if (i < n) rp[i] += bsum[i >> 8];
    if (i == 0) rp[n] = e;
}

// ---------------- CSR fill ----------------

__global__ void fill_kernel(const int* __restrict__ src, const int* __restrict__ dst,
                            const int* __restrict__ rp, int* __restrict__ cursor,
                            const float* __restrict__ dinv,
                            int* __restrict__ col, float* __restrict__ wval, int e) {
    int i = blockIdx.x * blockDim.x + threadIdx.x;
    if (i >= e) return;
    int d = dst[i];
    int s = src[i];
    int pos = rp[d] + atomicAdd(&cursor[d], 1);
    col[pos] = s;
    wval[pos] = dinv[s];
}

// ---------------- gather SpMM hop ----------------

__global__ __launch_bounds__(256) void spmm_gather_kernel(const int* __restrict__ rp,
                                                          const int* __restrict__ col,
                                                          const float* __restrict__ wval,
                                                          const float* __restrict__ dinv,
                                                          const float* __restrict__ hin,
                                                          float* __restrict__ hout, int n) {
    int t = blockIdx.x * 256 + threadIdx.x;
    int node = t >> 4;
    int j = t & 15;
    if (node >= n) return;
    int e0 = rp[node];
    int e1 = rp[node + 1];
    float di = dinv[node];
    const float4* hin4 = (const float4*)hin;
    float4 acc = hin4[(size_t)node * 16 + j];
    acc.x *= di; acc.y *= di; acc.z *= di; acc.w *= di;
    for (int e = e0; e < e1; ++e) {
        int s = col[e];
        float w = wval[e];
        float4 v = hin4[(size_t)s * 16 + j];
        acc.x = fmaf(w, v.x, acc.x);
        acc.y = fmaf(w, v.y, acc.y);
        acc.z = fmaf(w, v.z, acc.z);
        acc.w = fmaf(w, v.w, acc.w);
    }
    acc.x *= di; acc.y *= di; acc.z *= di; acc.w *= di;
    ((float4*)hout)[(size_t)node * 16 + j] = acc;
}

// ---------------- output GEMM via bf16 MFMA ----------------
// out[node][c] = sum_k feats[node][k] * W[k][c] + b[c]; feats = [x|h1|h2]
// Block: 256 thr = 4 waves; M-tile 64 nodes (16/wave), N=64, K=192.
// W staged once per block as transposed bf16 LDS [64][200] (pad -> <=2-way conflict).
// A-frags read direct from global fp32, converted to bf16 in-reg (RNE).

#define WT_LD 200  // padded leading dim (bf16 elems)

static __device__ inline short f2bf(float f) {
    unsigned u = __float_as_uint(f);
    u += 0x7fffu + ((u >> 16) & 1u);  // round-to-nearest-even
    return (short)(u >> 16);
}

__global__ __launch_bounds__(256) void gemm_mfma_kernel(const float* __restrict__ x,
                                                        const float* __restrict__ h1,
                                                        const float* __restrict__ h2,
                                                        const float* __restrict__ W,
                                                        const float* __restrict__ b,
                                                        float* __restrict__ out, int n) {
    __shared__ short sWt[64 * WT_LD];  // 25.6 KB, sWt[c][k] = bf16(W[k][c])
    int tid = threadIdx.x;

    // stage W transposed -> bf16
    for (int i = tid; i < 192 * 64; i += 256) {
        int k = i >> 6;
        int c = i & 63;
        sWt[c * WT_LD + k] = f2bf(W[i]);
    }
    __syncthreads();

    int w = tid >> 6;        // wave 0..3
    int l = tid & 63;        // lane
    int lr = l & 15;         // A row / D col
    int lk = l >> 4;         // 0..3 -> k-subslice
    int rbase = blockIdx.x * 64 + w * 16;  // this wave's 16 rows

    int node = rbase + lr;
    int node_ld = node < n ? node : (n - 1);  // clamp for loads

    f32x4 acc[4] = {{0.f, 0.f, 0.f, 0.f}, {0.f, 0.f, 0.f, 0.f},
                    {0.f, 0.f, 0.f, 0.f}, {0.f, 0.f, 0.f, 0.f}};

    const float* srcs[3] = {x, h1, h2};
#pragma unroll
    for (int kt = 0; kt < 6; ++kt) {
        const float* sp = srcs[kt >> 1];
        int kb = (kt & 1) * 32 + lk * 8;  // within-source k offset of this lane's 8 elems
        const float4* ap = (const float4*)(sp + (size_t)node_ld * D_FEAT + kb);
        float4 a0 = ap[0];
        float4 a1 = ap[1];
        bf16x8 af;
        af[0] = f2bf(a0.x); af[1] = f2bf(a0.y); af[2] = f2bf(a0.z); af[3] = f2bf(a0.w);
        af[4] = f2bf(a1.x); af[5] = f2bf(a1.y); af[6] = f2bf(a1.z); af[7] = f2bf(a1.w);
        int kg = kt * 32 + lk * 8;  // global k of B-frag
#pragma unroll
        for (int nt = 0; nt < 4; ++nt) {
            int c = nt * 16 + lr;
            bf16x8 bf = *(const bf16x8*)&sWt[c * WT_LD + kg];
            acc[nt] = __builtin_amdgcn_mfma_f32_16x16x32_bf16(af, bf, acc[nt], 0, 0, 0);
        }
    }

    // store: D[row=(l>>4)*4+i][col=lr] per n-tile
#pragma unroll
    for (int nt = 0; nt < 4; ++nt) {
        int c = nt * 16 + lr;
        float bias = b[c];
#pragma unroll
        for (int i = 0; i < 4; ++i) {
            int row = rbase + lk * 4 + i;
            if (row < n) out[(size_t)row * D_FEAT + c] = acc[nt][i] + bias;
        }
    }
}

// ---------------- launch ----------------

static inline size_t align256(size_t x) { return (x + 255) & ~(size_t)255; }

extern "C" void kernel_launch(void* const* d_in, const int* in_sizes, int n_in,
                              void* d_out, int out_size, void* d_ws, size_t ws_size,
                              hipStream_t stream) {
    const float* x  = (const float*)d_in[0];
    const int*   ei = (const int*)d_in[1];
    const float* W  = (const float*)d_in[2];
    const float* b  = (const float*)d_in[3];
    float* out = (float*)d_out;

    int N = in_sizes[0] / D_FEAT;
    int E = in_sizes[1] / 2;
    const int* src = ei;
    const int* dst = ei + E;

    char* base = (char*)d_ws;
    size_t off = 0;
    int* count  = (int*)(base + off);  off = align256(off + (size_t)N * 4);
    int* cursor = (int*)(base + off);  off = align256(off + (size_t)N * 4);
    int* rp     = (int*)(base + off);  off = align256(off + ((size_t)N + 1) * 4);
    int* bsum   = (int*)(base + off);  off = align256(off + 4096);
    float* dinv = (float*)(base + off); off = align256(off + (size_t)N * 4);
    int* col    = (int*)(base + off);  off = align256(off + (size_t)E * 4);
    float* wval = (float*)(base + off); off = align256(off + (size_t)E * 4);
    float* h1   = (float*)(base + off); off = align256(off + (size_t)N * D_FEAT * 4);
    float* h2   = (float*)(base + off); off = align256(off + (size_t)N * D_FEAT * 4);

    const int BS = 256;
    int gN   = (N + BS - 1) / BS;
    int gE   = (E + BS - 1) / BS;
    int nb   = gN;
    int gN16 = (int)(((long long)N * 16 + BS - 1) / BS);
    int gGemm = (N + 63) / 64;

    zero_int_kernel<<<gN, BS, 0, stream>>>(count, N);
    zero_int_kernel<<<gN, BS, 0, stream>>>(cursor, N);
    count_kernel<<<gE, BS, 0, stream>>>(dst, count, E);
    dinv_kernel<<<gN, BS, 0, stream>>>(count, dinv, N);
    scan_block_kernel<<<nb, BS, 0, stream>>>(count, rp, bsum, N);
    scan_sums_kernel<<<1, 64, 0, stream>>>(bsum, nb);
    scan_add_kernel<<<gN, BS, 0, stream>>>(rp, bsum, N, E);
    fill_kernel<<<gE, BS, 0, stream>>>(src, dst, rp, cursor, dinv, col, wval, E);
    spmm_gather_kernel<<<gN16, BS, 0, stream>>>(rp, col, wval, dinv, x, h1, N);
    spmm_gather_kernel<<<gN16, BS, 0, stream>>>(rp, col, wval, dinv, h1, h2, N);
    gemm_mfma_kernel<<<gGemm, BS, 0, stream>>>(x, h1, h2, W, b, out, N);
}